// Round 14
// baseline (810.593 us; speedup 1.0000x reference)
//
#include <hip/hip_runtime.h>

typedef __attribute__((ext_vector_type(8))) __bf16 bf16x8;
typedef __attribute__((ext_vector_type(4))) float f32x4;
typedef unsigned short u16;
typedef unsigned int u32;

__device__ __forceinline__ u16 f2bf(float x){
  u32 u = __float_as_uint(x);
  return (u16)((u + 0x7fffu + ((u >> 16) & 1u)) >> 16);
}
__device__ __forceinline__ u32 pkbf(float lo, float hi){
  u32 r; asm("v_cvt_pk_bf16_f32 %0, %1, %2" : "=v"(r) : "v"(lo), "v"(hi)); return r;
}

union FragU { uint4 u4; bf16x8 bf; };

__device__ __forceinline__ bf16x8 lds_frag(const unsigned char* smem, int off, int row, int strideB, int kElem){
  int byte = (row * strideB + kElem * 2) ^ ((row & 7) << 4);
  FragU f; f.u4 = *reinterpret_cast<const uint4*>(smem + off + byte);
  return f.bf;
}

typedef __attribute__((address_space(3))) unsigned char lds_u8;
typedef __attribute__((address_space(1))) const unsigned char g_u8;
__device__ __forceinline__ void glds16(const void* g, void* l){
  __builtin_amdgcn_global_load_lds((g_u8*)g, (lds_u8*)l, 16, 0, 0);
}

__global__ void prep_weights(const float* __restrict__ wq, const float* __restrict__ wp,
                             u16* __restrict__ wqb, u16* __restrict__ wpb){
  int i = blockIdx.x * 256 + threadIdx.x;
  wqb[i] = f2bf(wq[i]);              // grid sized exactly for 442368
  if (i < 147456) wpb[i] = f2bf(wp[i]);
}

// x f32 -> bf16, linear [147456][384]
__global__ void prep_x(const float* __restrict__ x, u16* __restrict__ xb){
  size_t i = ((size_t)blockIdx.x * 256 + threadIdx.x) * 8;
  float4 f0 = *reinterpret_cast<const float4*>(x + i);
  float4 f1 = *reinterpret_cast<const float4*>(x + i + 4);
  uint4 q;
  q.x = pkbf(f0.x, f0.y); q.y = pkbf(f0.z, f0.w);
  q.z = pkbf(f1.x, f1.y); q.w = pkbf(f1.z, f1.w);
  *reinterpret_cast<uint4*>(xb + i) = q;
}

// ======================================================================
// K2 v14: FULLY FUSED per-window qkv + RoPE + attention.
// One window per block, 256 thr (4 waves). A [80][384] staged ONCE.
// Per head: B [192][64] dbuf per k-tile (1 barrier/tile, prefetch for
// h+1 rides across the attention phase), GEMM -> epilogue (RoPE; q/k ->
// LDS [tok][64], v -> LDS vT [64][80], all register-sourced) -> attention
// (QK^T, masked softmax, P-via-shfl PV) -> attnout bf16 to axb rows
// (exclusively owned by this block; read-before-write within block).
// q/k/v never touch HBM.
// ======================================================================
#define FA   0          // A [80][384] swz : 61440
#define FB   61440      // B dbuf 2 x [192][64] swz : 49152 -> 110592
#define FBS  24576
#define FQ   110592     // q [80][64] swz : 10240
#define FK   120832     // k [80][64] swz : 10240
#define FV   131072     // vT [64][80] raw + 256 guard : 10496
#define FTC  141568     // 288 f32
#define FTS  142720     // -> 143872
__launch_bounds__(256, 1)
__global__ void fused_win(const u16* __restrict__ xb, const u16* __restrict__ wqb,
                          const float* __restrict__ bq, float* __restrict__ out,
                          u16* __restrict__ axb)
{
  __shared__ __align__(16) unsigned char smem[143872];
  const int tid  = threadIdx.x;
  const int wave = tid >> 6;            // also wc = 48-col quarter of N=192
  const int lane = tid & 63;
  const int l15  = lane & 15;
  const int lhi  = lane >> 4;

  const int bid  = blockIdx.x;
  const int g    = (bid & 7) * 256 + (bid >> 3);   // XCD swizzle (2048 = 8*256)
  const int bIdx = g >> 10;
  const int win  = g & 1023;
  const int wi   = win >> 5;
  const int wj   = win & 31;
  const bool maskWin = (wi == 31);

  auto rowof = [&](int t)->size_t {
    int r = t / 12, c = t - r * 12;
    int hh = wi * 6 + r + 3;  if (hh >= 192) hh -= 192;
    int ww = wj * 12 + c + 6; if (ww >= 384) ww -= 384;
    return ((size_t)bIdx * 192 + hh) * 384 + ww;
  };

  float* tabc = reinterpret_cast<float*>(smem + FTC);
  float* tabs = reinterpret_cast<float*>(smem + FTS);
  for (int i = tid; i < 288; i += 256){           // grid-stride (288 > 256!)
    int pos = i >> 4, m = i & 15;
    float pv = (pos < 6) ? (float)pos : (float)(pos - 6);
    float ang = pv * __expf(-(float)m * 0.5756462732485114f); // 10000^(-m/16)
    tabc[i] = cosf(ang);
    tabs[i] = sinf(ang);
  }
  // zero vT guard (overhang reads beyond ch63 row land here; must be finite 0)
  if (tid < 64) *reinterpret_cast<u32*>(smem + FV + 10240 + tid * 4) = 0u;

  // ---- stage A once: [80][384] bf16, 3840 chunks (rows gathered) ----
  #pragma unroll
  for (int it = 0; it < 15; ++it){
    int c   = it * 256 + tid;
    int row = c / 48;
    int p   = c - row * 48;
    int tc  = (row < 72) ? row : 71;
    int s   = (p & ~7) | ((p & 7) ^ (row & 7));
    glds16(xb + rowof(tc) * 384 + s * 8, smem + FA + c * 16);
  }

  // B stage: [192][64] for (head h, k-tile kk) -> bufOff
  auto stageB = [&](int h, int kk, int bufOff){
    #pragma unroll
    for (int it = 0; it < 6; ++it){
      int c = it * 256 + tid;
      int n = c >> 3, p = c & 7;
      size_t wrow = (size_t)((n >> 6) * 384 + h * 64 + (n & 63));
      glds16(wqb + wrow * 384 + kk * 64 + ((p ^ (n & 7)) << 3),
             smem + bufOff + c * 16);
    }
  };

  stageB(0, 0, FB);
  __syncthreads();                      // A + B(0,0) + tables + guard visible

  float sv[2][5][4];
  #pragma unroll
  for (int qi = 0; qi < 2; ++qi)
    #pragma unroll
    for (int a2 = 0; a2 < 5; ++a2)
      #pragma unroll
      for (int b2 = 0; b2 < 4; ++b2) sv[qi][a2][b2] = 0.0f;

  int cur = 0;
  for (int h = 0; h < 6; ++h){
    // ================= per-head GEMM: M=80, N=192 (q|k|v), K=384 =================
    f32x4 acc[5][3];
    #pragma unroll
    for (int mt = 0; mt < 5; ++mt)
      #pragma unroll
      for (int nt = 0; nt < 3; ++nt) acc[mt][nt] = 0.0f;

    for (int kk = 0; kk < 6; ++kk){
      if (kk < 5) stageB(h, kk + 1, FB + (cur ^ 1) * FBS);
      #pragma unroll
      for (int ks = 0; ks < 2; ++ks){
        const int kEl = kk * 64 + ks * 32 + lhi * 8;
        const int bEl = ks * 32 + lhi * 8;
        bf16x8 afr[5], bfr[3];
        #pragma unroll
        for (int mt = 0; mt < 5; ++mt)
          afr[mt] = lds_frag(smem, FA, mt * 16 + l15, 768, kEl);
        #pragma unroll
        for (int nt = 0; nt < 3; ++nt)
          bfr[nt] = lds_frag(smem, FB + cur * FBS, wave * 48 + nt * 16 + l15, 128, bEl);
        __builtin_amdgcn_s_setprio(1);
        #pragma unroll
        for (int mt = 0; mt < 5; ++mt)
          #pragma unroll
          for (int nt = 0; nt < 3; ++nt)
            acc[mt][nt] = __builtin_amdgcn_mfma_f32_16x16x32_bf16(afr[mt], bfr[nt], acc[mt][nt], 0, 0, 0);
        __builtin_amdgcn_s_setprio(0);
      }
      __syncthreads();                  // drains prefetch; protects cur^1
      if (kk < 5) cur ^= 1;
    }

    // ================= epilogue: bias + RoPE; q/k/vT -> LDS (reg-sourced) =========
    #pragma unroll
    for (int nt = 0; nt < 3; ++nt){
      const int ch  = wave * 48 + nt * 16 + l15;   // 0..191; 16-blocks don't cross secs
      const int sec = ch >> 6;                     // 0=q,1=k,2=v
      const int chh = ch & 63;
      const float bias = bq[sec * 384 + h * 64 + chh];
      if (sec < 2){
        const int p2 = chh >> 1;
        const int m  = p2 & 15;
        const bool isR = (p2 < 16);
        const bool ev  = ((chh & 1) == 0);
        const int dstOff = sec ? FK : FQ;
        #pragma unroll
        for (int mt = 0; mt < 5; ++mt){
          #pragma unroll
          for (int r = 0; r < 4; ++r){
            const int tok = mt * 16 + lhi * 4 + r;
            float v = acc[mt][nt][r] + bias;
            float o = __shfl_xor(v, 1);
            int tr = tok / 12;
            int pos = isR ? tr : (6 + tok - tr * 12);
            float cc = tabc[pos * 16 + m], ssn = tabs[pos * 16 + m];
            float nv = ev ? (v * cc - o * ssn) : (o * ssn + v * cc);
            if (sec == 0) nv *= 0.125f;
            int byte = (tok * 128 + chh * 2) ^ ((tok & 7) << 4);
            *reinterpret_cast<u16*>(smem + dstOff + byte) = f2bf(nv);
          }
        }
      } else {
        #pragma unroll
        for (int mt = 0; mt < 5; ++mt){
          const int tok0 = mt * 16 + lhi * 4;
          uint2 pk;
          pk.x = pkbf(acc[mt][nt][0] + bias, acc[mt][nt][1] + bias);
          pk.y = pkbf(acc[mt][nt][2] + bias, acc[mt][nt][3] + bias);
          *reinterpret_cast<uint2*>(smem + FV + chh * 160 + tok0 * 2) = pk;
        }
      }
    }
    __syncthreads();                    // q/k/vT published

    if (h < 5) stageB(h + 1, 0, FB + (cur ^ 1) * FBS);  // rides across attention

    // ================= attention (win_attn6 body; wave3 takes q-tile 4 too) ======
    const int nqi = (wave == 3) ? 2 : 1;
    for (int qi = 0; qi < nqi; ++qi){
      const int qt   = qi ? 4 : wave;
      const int qtok = qt * 16 + l15;
      const bool tv  = (qtok < 72);

      f32x4 pf[5];
      #pragma unroll
      for (int nt = 0; nt < 5; ++nt) pf[nt] = 0.0f;
      __builtin_amdgcn_s_setprio(1);
      #pragma unroll
      for (int ks = 0; ks < 2; ++ks){
        const int kEl = ks * 32 + lhi * 8;
        bf16x8 qf = lds_frag(smem, FQ, qtok, 128, kEl);
        #pragma unroll
        for (int nt = 0; nt < 5; ++nt){
          bf16x8 kf = lds_frag(smem, FK, nt * 16 + l15, 128, kEl);
          pf[nt] = __builtin_amdgcn_mfma_f32_16x16x32_bf16(kf, qf, pf[nt], 0, 0, 0);
        }
      }
      __builtin_amdgcn_s_setprio(0);

      float mx = -1e30f;
      #pragma unroll
      for (int nt = 0; nt < 5; ++nt)
        #pragma unroll
        for (int r = 0; r < 4; ++r){
          const int kk2 = nt * 16 + lhi * 4 + r;
          bool valid = (kk2 < 72) && (!maskWin || ((kk2 < 36) == (qtok < 36)));
          float val = valid ? pf[nt][r] : -1e30f;
          pf[nt][r] = val;
          mx = fmaxf(mx, val);
        }
      mx = fmaxf(mx, __shfl_xor(mx, 16));
      mx = fmaxf(mx, __shfl_xor(mx, 32));
      float sm = 0.0f;
      #pragma unroll
      for (int nt = 0; nt < 5; ++nt)
        #pragma unroll
        for (int r = 0; r < 4; ++r){
          float e = __expf(pf[nt][r] - mx);
          pf[nt][r] = e; sm += e;
        }
      sm += __shfl_xor(sm, 16);
      sm += __shfl_xor(sm, 32);
      const float inv = 1.0f / sm;
      u32 pp[5][2];
      #pragma unroll
      for (int nt = 0; nt < 5; ++nt){
        float p0 = pf[nt][0] * inv, p1 = pf[nt][1] * inv;
        float p2 = pf[nt][2] * inv, p3 = pf[nt][3] * inv;
        sv[qi][nt][0] += p0; sv[qi][nt][1] += p1;
        sv[qi][nt][2] += p2; sv[qi][nt][3] += p3;
        pp[nt][0] = pkbf(p0, p1);
        pp[nt][1] = pkbf(p2, p3);
      }

      f32x4 oacc[4];
      #pragma unroll
      for (int nt = 0; nt < 4; ++nt) oacc[nt] = 0.0f;
      #pragma unroll
      for (int ks = 0; ks < 3; ++ks){
        FragU pb;
        u32 w[4];
        #pragma unroll
        for (int w_ = 0; w_ < 4; ++w_){
          int srcLane = l15 + 16 * ((lane >> 4 & 1) * 2 + (w_ >> 1));
          u32 c0 = __shfl(pp[ks * 2][w_ & 1], srcLane);
          u32 c1 = (ks * 2 + 1 < 5) ? __shfl(pp[ks * 2 + 1][w_ & 1], srcLane) : 0u;
          w[w_] = (lhi & 2) ? c1 : c0;
        }
        pb.u4.x = w[0]; pb.u4.y = w[1]; pb.u4.z = w[2]; pb.u4.w = w[3];
        const int kEl = ks * 32 + lhi * 8;
        __builtin_amdgcn_s_setprio(1);
        #pragma unroll
        for (int nt = 0; nt < 4; ++nt){
          FragU vf;
          vf.u4 = *reinterpret_cast<const uint4*>(smem + FV + (nt * 16 + l15) * 160 + kEl * 2);
          oacc[nt] = __builtin_amdgcn_mfma_f32_16x16x32_bf16(vf.bf, pb.bf, oacc[nt], 0, 0, 0);
        }
        __builtin_amdgcn_s_setprio(0);
      }
      if (tv){
        u16* ao = axb + rowof(qtok) * 384 + h * 64;
        #pragma unroll
        for (int nt = 0; nt < 4; ++nt){
          uint2 pk;
          pk.x = pkbf(oacc[nt][0], oacc[nt][1]);
          pk.y = pkbf(oacc[nt][2], oacc[nt][3]);
          *reinterpret_cast<uint2*>(ao + nt * 16 + lhi * 4) = pk;
        }
      }
    } // qi
    __syncthreads();                    // attention LDS reads done; drains prefetch
    if (h < 5) cur ^= 1;
  } // heads

  // ================= save_attn = mean over heads =================
  const int nqi = (wave == 3) ? 2 : 1;
  for (int qi = 0; qi < nqi; ++qi){
    const int qt   = qi ? 4 : wave;
    const int qtok = qt * 16 + l15;
    if (qtok < 72){
      float* so = out + 56623104ull + (size_t)g * 5184 + (size_t)qtok * 72;
      const float c6 = 1.0f / 6.0f;
      #pragma unroll
      for (int nt = 0; nt < 4; ++nt){
        float4 v4;
        v4.x = sv[qi][nt][0]*c6; v4.y = sv[qi][nt][1]*c6;
        v4.z = sv[qi][nt][2]*c6; v4.w = sv[qi][nt][3]*c6;
        *reinterpret_cast<float4*>(so + nt * 16 + lhi * 4) = v4;
      }
      if (lhi < 2){
        float4 v4;
        v4.x = sv[qi][4][0]*c6; v4.y = sv[qi][4][1]*c6;
        v4.z = sv[qi][4][2]*c6; v4.w = sv[qi][4][3]*c6;
        *reinterpret_cast<float4*>(so + 64 + lhi * 4) = v4;
      }
    }
  }
}

// ======================================================================
// K4: out-projection GEMM (r12): tile M=128 x N=192, BK=32, 2-phase dbuf
// B, A frags from axb; flat grid 2304 with XCD co-location of ny-pairs.
// ======================================================================
#define B6STR 12288
__launch_bounds__(512, 4)
__global__ void proj_gemm2(const u16* __restrict__ axb,
                           const u16* __restrict__ wpb, const float* __restrict__ bp,
                           float* __restrict__ out)
{
  __shared__ __align__(16) unsigned char smem[24576];
  const int tid  = threadIdx.x;
  const int wave = tid >> 6;
  const int lane = tid & 63;
  const int l15  = lane & 15;
  const int lhi  = lane >> 4;
  const int wr   = wave >> 2;
  const int wc   = wave & 3;

  const int bid = blockIdx.x;           // 0..2303
  const int l   = (bid & 7) * 288 + (bid >> 3);
  const size_t row0 = (size_t)(l >> 1) * 128;
  const int ny  = l & 1;

  const u16* bsec = wpb + (size_t)(ny * 192) * 384;
  auto stageB = [&](int t, int bufOff){
    {
      int c = tid, row = c >> 2, ccd = c & 3;
      int ccs = ccd ^ ((row >> 1) & 3);
      glds16(bsec + (size_t)row * 384 + t * 32 + ccs * 8, smem + bufOff + c * 16);
    }
    if (tid < 256){
      int c = 512 + tid, row = c >> 2, ccd = c & 3;
      int ccs = ccd ^ ((row >> 1) & 3);
      glds16(bsec + (size_t)row * 384 + t * 32 + ccs * 8, smem + bufOff + c * 16);
    }
  };

  const u16* abase = axb + (row0 + wr * 64 + l15) * 384 + lhi * 8;

  f32x4 acc[4][3];
  #pragma unroll
  for (int mt = 0; mt < 4; ++mt)
    #pragma unroll
    for (int nt = 0; nt < 3; ++nt) acc[mt][nt] = 0.0f;

  FragU a_cur[4], a_nxt[4];
  #pragma unroll
  for (int mt = 0; mt < 4; ++mt)
    a_cur[mt].u4 = *reinterpret_cast<const uint4*>(abase + mt * 6144);
  stageB(0, 0);
  __syncthreads();

  int buf = 0;
  for (int t = 0; t < 12; ++t){
    if (t < 11){
      stageB(t + 1, buf ^ B6STR);
      #pragma unroll
      for (int mt = 0; mt < 4; ++mt)
        a_nxt[mt].u4 = *reinterpret_cast<const uint4*>(abase + mt * 6144 + (t + 1) * 32);
    }
    FragU bfr[3];
    #pragma unroll
    for (int nt = 0; nt < 3; ++nt){
      int rown = wc * 48 + nt * 16 + l15;
      int byte = buf + rown * 64 + ((lhi ^ ((rown >> 1) & 3)) << 4);
      bfr[nt].u4 = *reinterpret_cast<const uint4*>(smem + byte);
    }
    #pragma unroll
    for (int mt = 0; mt < 4; ++mt)
      #pragma unroll
      for (int nt = 0; nt < 3; ++nt)
        acc[mt][nt] = __builtin_amdgcn_mfma_f32_16x16x32_bf16(a_cur[mt].bf, bfr[nt].bf, acc[mt][nt], 0, 0, 0);
    __syncthreads();
    #pragma unroll
    for (int mt = 0; mt < 4; ++mt) a_cur[mt] = a_nxt[mt];
    buf ^= B6STR;
  }

  float bpv[3];
  #pragma unroll
  for (int nt = 0; nt < 3; ++nt) bpv[nt] = bp[ny * 192 + wc * 48 + nt * 16 + l15];
  #pragma unroll
  for (int mt = 0; mt < 4; ++mt)
    #pragma unroll
    for (int nt = 0; nt < 3; ++nt){
      const int ch = ny * 192 + wc * 48 + nt * 16 + l15;
      #pragma unroll
      for (int r = 0; r < 4; ++r){
        size_t grow = row0 + wr * 64 + mt * 16 + lhi * 4 + r;
        out[grow * 384 + ch] = acc[mt][nt][r] + bpv[nt];
      }
    }
}

extern "C" void kernel_launch(void* const* d_in, const int* in_sizes, int n_in,
                              void* d_out, int out_size, void* d_ws, size_t ws_size,
                              hipStream_t stream)
{
  const float* x  = (const float*)d_in[0];
  const float* wq = (const float*)d_in[1];
  const float* bq = (const float*)d_in[2];
  const float* wp = (const float*)d_in[3];
  const float* bp = (const float*)d_in[4];
  float* out = (float*)d_out;

  u16* wqb = (u16*)d_ws;                              // 442368 bf16
  u16* wpb = (u16*)((char*)d_ws + 442368 * 2);        // 147456 bf16
  u16* xb  = (u16*)((char*)d_ws + 127008768);         // 147456*384 bf16 (113.2 MB)
  // ws_size >= 240254976 confirmed by rounds 5/7/9 (big2 path ran).
  // fused_win reads its window's xb rows (drained at its first barrier) and
  // later overwrites exactly those rows with attnout bf16 -- exclusive
  // ownership (windows partition the rolled image), so in-place is race-free.

  prep_weights<<<1728, 256, 0, stream>>>(wq, wp, wqb, wpb);
  prep_x<<<27648, 256, 0, stream>>>(x, xb);
  fused_win<<<2048, 256, 0, stream>>>(xb, wqb, bq, out, xb);
  proj_gemm2<<<2304, 512, 0, stream>>>(xb, wpb, bp, out);
}

// Round 15
// 708.208 us; speedup vs baseline: 1.1446x; 1.1446x over previous
//
#include <hip/hip_runtime.h>

typedef __attribute__((ext_vector_type(8))) __bf16 bf16x8;
typedef __attribute__((ext_vector_type(4))) float f32x4;
typedef unsigned short u16;
typedef unsigned int u32;

__device__ __forceinline__ u16 f2bf(float x){
  u32 u = __float_as_uint(x);
  return (u16)((u + 0x7fffu + ((u >> 16) & 1u)) >> 16);
}
__device__ __forceinline__ u32 pkbf(float lo, float hi){
  u32 r; asm("v_cvt_pk_bf16_f32 %0, %1, %2" : "=v"(r) : "v"(lo), "v"(hi)); return r;
}

union FragU { uint4 u4; bf16x8 bf; };

__device__ __forceinline__ bf16x8 lds_frag(const unsigned char* smem, int off, int row, int strideB, int kElem){
  int byte = (row * strideB + kElem * 2) ^ ((row & 7) << 4);
  FragU f; f.u4 = *reinterpret_cast<const uint4*>(smem + off + byte);
  return f.bf;
}

typedef __attribute__((address_space(3))) unsigned char lds_u8;
typedef __attribute__((address_space(1))) const unsigned char g_u8;
__device__ __forceinline__ void glds16(const void* g, void* l){
  __builtin_amdgcn_global_load_lds((g_u8*)g, (lds_u8*)l, 16, 0, 0);
}

// ===== merged prep: x f32->bf16 (all blocks) + weights (blocks < 1728) =====
__global__ void prep_all(const float* __restrict__ x, u16* __restrict__ xb,
                         const float* __restrict__ wq, const float* __restrict__ wp,
                         u16* __restrict__ wqb, u16* __restrict__ wpb){
  const int bidx = blockIdx.x;
  size_t i = ((size_t)bidx * 256 + threadIdx.x) * 8;
  float4 f0 = *reinterpret_cast<const float4*>(x + i);
  float4 f1 = *reinterpret_cast<const float4*>(x + i + 4);
  uint4 q;
  q.x = pkbf(f0.x, f0.y); q.y = pkbf(f0.z, f0.w);
  q.z = pkbf(f1.x, f1.y); q.w = pkbf(f1.z, f1.w);
  *reinterpret_cast<uint4*>(xb + i) = q;
  if (bidx < 1728){
    int j = bidx * 256 + threadIdx.x;
    wqb[j] = f2bf(wq[j]);               // 1728*256 == 442368 exactly
    if (j < 147456) wpb[j] = f2bf(wp[j]);
  }
}

// ======================================================================
// K2: WINDOW-MAJOR qkv GEMM (r11 proven, 296us). One (window, sec) per
// block, 256 thr. q/k window-head-tiled into out; v transposed in LDS to
// vws[g][h][64ch][80tok] (toks 72..79 zeroed). Stage(kk=0) issued before
// the trig table build to hide first-tile latency under VALU.
// ======================================================================
#define WA_OFF 0        // A [80][64] bf16 swz : 10240
#define WB_OFF 10240    // B [384][64] bf16 swz : 49152 -> 59392
#define WVT    0        // v-transpose [384ch][80tok] (aliases A+B post-loop)
#define WTC    61440    // 288 f32
#define WTS    62592    // -> 63744
__launch_bounds__(256, 2)
__global__ void qkv_win(const u16* __restrict__ xb, const u16* __restrict__ wqb,
                        const float* __restrict__ bq, float* __restrict__ out,
                        u16* __restrict__ vws)
{
  __shared__ __align__(16) unsigned char smem[63744];
  const int tid  = threadIdx.x;
  const int wc   = tid >> 6;            // wave 0..3 : 96-col quarter
  const int lane = tid & 63;
  const int l15  = lane & 15;
  const int lhi  = lane >> 4;

  const int bid = blockIdx.x;           // 0..6143 (= 8 * 768)
  const int l   = (bid & 7) * 768 + (bid >> 3);
  const int g   = l / 3;                // global window 0..2047
  const int sec = l - g * 3;            // 0=q,1=k,2=v
  const int bIdx = g >> 10;
  const int win  = g & 1023;
  const int wi   = win >> 5;
  const int wj   = win & 31;

  auto rowof = [&](int t)->size_t {
    int r = t / 12, c = t - r * 12;
    int hh = wi * 6 + r + 3;  if (hh >= 192) hh -= 192;
    int ww = wj * 12 + c + 6; if (ww >= 384) ww -= 384;
    return ((size_t)bIdx * 192 + hh) * 384 + ww;
  };

  // precompute A-chunk source rows (kk-invariant)
  size_t arow[3]; int asoff[3]; bool aval[3];
  #pragma unroll
  for (int it = 0; it < 3; ++it){
    int c = it * 256 + tid;
    aval[it] = (it < 2) || (tid < 128);
    int t = c >> 3, p = c & 7;
    int tc = (t < 72) ? t : 71;
    arow[it]  = rowof(tc);
    asoff[it] = ((p ^ (t & 7)) << 3);
  }

  // issue k-tile 0 staging FIRST (latency hides under table trig below)
  #pragma unroll
  for (int it = 0; it < 3; ++it){
    if (aval[it])
      glds16(xb + arow[it] * 384 + asoff[it],
             smem + WA_OFF + (it * 256 + tid) * 16);
  }
  #pragma unroll
  for (int it = 0; it < 12; ++it){
    int c = it * 256 + tid;
    int n = c >> 3, p = c & 7;
    glds16(wqb + (size_t)(sec * 384 + n) * 384 + ((p ^ (n & 7)) << 3),
           smem + WB_OFF + c * 16);
  }

  float* tabc = reinterpret_cast<float*>(smem + WTC);
  float* tabs = reinterpret_cast<float*>(smem + WTS);
  for (int i = tid; i < 288; i += 256){
    int pos = i >> 4, m = i & 15;
    float pv = (pos < 6) ? (float)pos : (float)(pos - 6);
    float ang = pv * __expf(-(float)m * 0.5756462732485114f); // 10000^(-m/16)
    tabc[i] = cosf(ang);
    tabs[i] = sinf(ang);
  }

  f32x4 acc[5][6];
  #pragma unroll
  for (int mt = 0; mt < 5; ++mt)
    #pragma unroll
    for (int nt = 0; nt < 6; ++nt) acc[mt][nt] = 0.0f;

  for (int kk = 0; kk < 6; ++kk){
    if (kk > 0){
      #pragma unroll
      for (int it = 0; it < 3; ++it){
        if (aval[it])
          glds16(xb + arow[it] * 384 + kk * 64 + asoff[it],
                 smem + WA_OFF + (it * 256 + tid) * 16);
      }
      #pragma unroll
      for (int it = 0; it < 12; ++it){
        int c = it * 256 + tid;
        int n = c >> 3, p = c & 7;
        glds16(wqb + (size_t)(sec * 384 + n) * 384 + kk * 64 + ((p ^ (n & 7)) << 3),
               smem + WB_OFF + c * 16);
      }
    }
    __syncthreads();
    #pragma unroll
    for (int ks = 0; ks < 2; ++ks){
      const int kEl = ks * 32 + lhi * 8;
      bf16x8 af[5], bfr[6];
      #pragma unroll
      for (int mt = 0; mt < 5; ++mt)
        af[mt] = lds_frag(smem, WA_OFF, mt * 16 + l15, 128, kEl);
      #pragma unroll
      for (int nt = 0; nt < 6; ++nt)
        bfr[nt] = lds_frag(smem, WB_OFF, wc * 96 + nt * 16 + l15, 128, kEl);
      __builtin_amdgcn_s_setprio(1);
      #pragma unroll
      for (int mt = 0; mt < 5; ++mt)
        #pragma unroll
        for (int nt = 0; nt < 6; ++nt)
          acc[mt][nt] = __builtin_amdgcn_mfma_f32_16x16x32_bf16(af[mt], bfr[nt], acc[mt][nt], 0, 0, 0);
      __builtin_amdgcn_s_setprio(0);
    }
    __syncthreads();
  }

  if (sec < 2){
    u16* qk = (u16*)out + (sec ? 56623104u : 0u) + (size_t)g * 27648;  // 6*4608
    #pragma unroll
    for (int nt = 0; nt < 6; ++nt){
      const int ch  = wc * 96 + nt * 16 + l15;
      const int h   = ch >> 6;
      const int chh = ch & 63;
      const float bias = bq[sec * 384 + ch];
      const int p2  = chh >> 1;
      const int m   = p2 & 15;
      const bool isR = (p2 < 16);
      const bool ev  = ((chh & 1) == 0);
      #pragma unroll
      for (int mt = 0; mt < 5; ++mt){
        #pragma unroll
        for (int r = 0; r < 4; ++r){
          const int tok = mt * 16 + lhi * 4 + r;
          float v = acc[mt][nt][r] + bias;
          float o = __shfl_xor(v, 1);
          int tr = tok / 12;
          int pos = isR ? tr : (6 + tok - tr * 12);
          float cc = tabc[pos * 16 + m], ssn = tabs[pos * 16 + m];
          float nv = ev ? (v * cc - o * ssn) : (o * ssn + v * cc);
          if (sec == 0) nv *= 0.125f;
          if (tok < 72)
            qk[(size_t)h * 4608 + tok * 64 + chh] = f2bf(nv);
        }
      }
    }
  } else {
    #pragma unroll
    for (int nt = 0; nt < 6; ++nt){
      const int ch = wc * 96 + nt * 16 + l15;
      const float bv = bq[768 + ch];
      #pragma unroll
      for (int mt = 0; mt < 5; ++mt){
        const int tok0 = mt * 16 + lhi * 4;
        uint2 pk;
        pk.x = pkbf(acc[mt][nt][0] + bv, acc[mt][nt][1] + bv);
        pk.y = pkbf(acc[mt][nt][2] + bv, acc[mt][nt][3] + bv);
        *reinterpret_cast<uint2*>(smem + WVT + ch * 160 + tok0 * 2) = pk;
      }
    }
    __syncthreads();
    u16* vd = vws + (size_t)g * 30720;   // 6*64*80
    #pragma unroll
    for (int it = 0; it < 15; ++it){
      int c  = it * 256 + tid;           // 0..3839
      int ch = c / 10;
      int p  = c - ch * 10;
      uint4 val;
      if (p == 9){ val.x = 0; val.y = 0; val.z = 0; val.w = 0; }  // tok 72..79 = 0
      else val = *reinterpret_cast<const uint4*>(smem + WVT + c * 16);
      *reinterpret_cast<uint4*>(vd + (size_t)(ch >> 6) * 5120 + (ch & 63) * 80 + p * 8) = val;
    }
  }
}

// ============ K3: per-window attention (r11 win_attn6, unchanged) ============
#define QH4 0
#define KH4 10240
#define VT4 20480      // 64*160 + 256 guard -> 30976
#define SMEM4 30976
__launch_bounds__(320, 5)
__global__ void win_attn6(const u16* __restrict__ qkg,
                          const u16* __restrict__ vws,
                          float* __restrict__ out,
                          u16* __restrict__ axb)
{
  __shared__ __align__(16) unsigned char smem[SMEM4];
  const int tid  = threadIdx.x;
  const int wave = tid >> 6;
  const int lane = tid & 63;
  const int l15  = lane & 15;
  const int lhi  = lane >> 4;

  const int bid  = blockIdx.x;
  const int wgid = (bid & 7) * 256 + (bid >> 3);   // XCD swizzle (2048 = 8*256)
  const int bIdx = wgid >> 10;
  const int win  = wgid & 1023;
  const int wi   = win >> 5;
  const int wj   = win & 31;
  const bool maskWin = (wi == 31);
  const int g    = wgid;

  auto rowof = [&](int t)->size_t {
    int r = t / 12, c = t - r * 12;
    int hh = wi * 6 + r + 3;  if (hh >= 192) hh -= 192;
    int ww = wj * 12 + c + 6; if (ww >= 384) ww -= 384;
    return ((size_t)bIdx * 192 + hh) * 384 + ww;
  };
  const int qtok = wave * 16 + l15;     // 0..79
  const bool tv = (qtok < 72);
  const size_t qrow = rowof(tv ? qtok : 71);

  const u16* qsl0 = qkg + (size_t)g * 27648;
  const u16* ksl0 = qkg + 56623104u + (size_t)g * 27648;
  const u16* vsl0 = vws + (size_t)g * 30720;

  // zero the VT guard (row-overhang reads for kEl>=80 land here)
  if (tid < 64) *reinterpret_cast<u32*>(smem + VT4 + 10240 + tid * 4) = 0u;

  float sv[5][4];
  #pragma unroll
  for (int a2 = 0; a2 < 5; ++a2)
    #pragma unroll
    for (int b2 = 0; b2 < 4; ++b2) sv[a2][b2] = 0.0f;

  for (int h = 0; h < 6; ++h){
    const u16* qsl = qsl0 + h * 4608;
    const u16* ksl = ksl0 + h * 4608;
    const u16* vsl = vsl0 + h * 5120;
    #pragma unroll
    for (int it = 0; it < 2; ++it){
      int c = it * 320 + tid;           // 0..639
      int t = c >> 3, p = c & 7;
      int tc = (t < 72) ? t : 71;
      int s = (p ^ (t & 7)) << 3;
      glds16(qsl + tc * 64 + s, smem + QH4 + c * 16);
      glds16(ksl + tc * 64 + s, smem + KH4 + c * 16);
      glds16(vsl + c * 8,       smem + VT4 + c * 16);
    }
    __syncthreads();                    // stage visible

    f32x4 pf[5];
    #pragma unroll
    for (int nt = 0; nt < 5; ++nt) pf[nt] = 0.0f;
    __builtin_amdgcn_s_setprio(1);
    #pragma unroll
    for (int ks = 0; ks < 2; ++ks){
      const int kEl = ks * 32 + lhi * 8;
      bf16x8 qf = lds_frag(smem, QH4, qtok, 128, kEl);
      #pragma unroll
      for (int nt = 0; nt < 5; ++nt){
        bf16x8 kf = lds_frag(smem, KH4, nt * 16 + l15, 128, kEl);
        pf[nt] = __builtin_amdgcn_mfma_f32_16x16x32_bf16(kf, qf, pf[nt], 0, 0, 0);
      }
    }
    __builtin_amdgcn_s_setprio(0);

    float mx = -1e30f;
    #pragma unroll
    for (int nt = 0; nt < 5; ++nt)
      #pragma unroll
      for (int r = 0; r < 4; ++r){
        const int kk2 = nt * 16 + lhi * 4 + r;
        bool valid = (kk2 < 72) && (!maskWin || ((kk2 < 36) == (qtok < 36)));
        float val = valid ? pf[nt][r] : -1e30f;
        pf[nt][r] = val;
        mx = fmaxf(mx, val);
      }
    mx = fmaxf(mx, __shfl_xor(mx, 16));
    mx = fmaxf(mx, __shfl_xor(mx, 32));
    float sm = 0.0f;
    #pragma unroll
    for (int nt = 0; nt < 5; ++nt)
      #pragma unroll
      for (int r = 0; r < 4; ++r){
        float e = __expf(pf[nt][r] - mx);
        pf[nt][r] = e; sm += e;
      }
    sm += __shfl_xor(sm, 16);
    sm += __shfl_xor(sm, 32);
    const float inv = 1.0f / sm;
    u32 pp[5][2];                       // packed bf16 pairs: P[k..k+1][q=l15]
    #pragma unroll
    for (int nt = 0; nt < 5; ++nt){
      float p0 = pf[nt][0] * inv, p1 = pf[nt][1] * inv;
      float p2 = pf[nt][2] * inv, p3 = pf[nt][3] * inv;
      sv[nt][0] += p0; sv[nt][1] += p1; sv[nt][2] += p2; sv[nt][3] += p3;
      pp[nt][0] = pkbf(p0, p1);
      pp[nt][1] = pkbf(p2, p3);
    }

    f32x4 oacc[4];
    #pragma unroll
    for (int nt = 0; nt < 4; ++nt) oacc[nt] = 0.0f;
    #pragma unroll
    for (int ks = 0; ks < 3; ++ks){
      FragU pb;
      u32 w[4];
      #pragma unroll
      for (int w_ = 0; w_ < 4; ++w_){
        int srcLane = l15 + 16 * ((lane >> 4 & 1) * 2 + (w_ >> 1));
        u32 c0 = __shfl(pp[ks * 2][w_ & 1], srcLane);
        u32 c1 = (ks * 2 + 1 < 5) ? __shfl(pp[ks * 2 + 1][w_ & 1], srcLane) : 0u;
        w[w_] = (lhi & 2) ? c1 : c0;
      }
      pb.u4.x = w[0]; pb.u4.y = w[1]; pb.u4.z = w[2]; pb.u4.w = w[3];
      const int kEl = ks * 32 + lhi * 8;
      __builtin_amdgcn_s_setprio(1);
      #pragma unroll
      for (int nt = 0; nt < 4; ++nt){
        FragU vf;
        vf.u4 = *reinterpret_cast<const uint4*>(smem + VT4 + (nt * 16 + l15) * 160 + kEl * 2);
        oacc[nt] = __builtin_amdgcn_mfma_f32_16x16x32_bf16(vf.bf, pb.bf, oacc[nt], 0, 0, 0);
      }
      __builtin_amdgcn_s_setprio(0);
    }
    if (tv){
      u16* ao = axb + qrow * 384 + h * 64;
      #pragma unroll
      for (int nt = 0; nt < 4; ++nt){
        uint2 pk;
        pk.x = pkbf(oacc[nt][0], oacc[nt][1]);
        pk.y = pkbf(oacc[nt][2], oacc[nt][3]);
        *reinterpret_cast<uint2*>(ao + nt * 16 + lhi * 4) = pk;
      }
    }
    __syncthreads();                    // all LDS reads done before next stage
  } // heads

  if (tv){
    float* so = out + 56623104ull + (size_t)wgid * 5184 + (size_t)qtok * 72;
    const float c6 = 1.0f / 6.0f;
    #pragma unroll
    for (int nt = 0; nt < 4; ++nt){
      float4 v4; v4.x = sv[nt][0]*c6; v4.y = sv[nt][1]*c6; v4.z = sv[nt][2]*c6; v4.w = sv[nt][3]*c6;
      *reinterpret_cast<float4*>(so + nt * 16 + lhi * 4) = v4;
    }
    if (lhi < 2){
      float4 v4; v4.x = sv[4][0]*c6; v4.y = sv[4][1]*c6; v4.z = sv[4][2]*c6; v4.w = sv[4][3]*c6;
      *reinterpret_cast<float4*>(so + 64 + lhi * 4) = v4;
    }
  }
}

// ======================================================================
// K4: out-projection GEMM (r12): tile M=128 x N=192, BK=32, 2-phase dbuf
// B, A frags from axb; flat grid 2304 with XCD co-location of ny-pairs.
// ======================================================================
#define B6STR 12288
__launch_bounds__(512, 4)
__global__ void proj_gemm2(const u16* __restrict__ axb,
                           const u16* __restrict__ wpb, const float* __restrict__ bp,
                           float* __restrict__ out)
{
  __shared__ __align__(16) unsigned char smem[24576];
  const int tid  = threadIdx.x;
  const int wave = tid >> 6;
  const int lane = tid & 63;
  const int l15  = lane & 15;
  const int lhi  = lane >> 4;
  const int wr   = wave >> 2;
  const int wc   = wave & 3;

  const int bid = blockIdx.x;           // 0..2303
  const int l   = (bid & 7) * 288 + (bid >> 3);
  const size_t row0 = (size_t)(l >> 1) * 128;
  const int ny  = l & 1;

  const u16* bsec = wpb + (size_t)(ny * 192) * 384;
  auto stageB = [&](int t, int bufOff){
    {
      int c = tid, row = c >> 2, ccd = c & 3;
      int ccs = ccd ^ ((row >> 1) & 3);
      glds16(bsec + (size_t)row * 384 + t * 32 + ccs * 8, smem + bufOff + c * 16);
    }
    if (tid < 256){
      int c = 512 + tid, row = c >> 2, ccd = c & 3;
      int ccs = ccd ^ ((row >> 1) & 3);
      glds16(bsec + (size_t)row * 384 + t * 32 + ccs * 8, smem + bufOff + c * 16);
    }
  };

  const u16* abase = axb + (row0 + wr * 64 + l15) * 384 + lhi * 8;

  f32x4 acc[4][3];
  #pragma unroll
  for (int mt = 0; mt < 4; ++mt)
    #pragma unroll
    for (int nt = 0; nt < 3; ++nt) acc[mt][nt] = 0.0f;

  FragU a_cur[4], a_nxt[4];
  #pragma unroll
  for (int mt = 0; mt < 4; ++mt)
    a_cur[mt].u4 = *reinterpret_cast<const uint4*>(abase + mt * 6144);
  stageB(0, 0);
  __syncthreads();

  int buf = 0;
  for (int t = 0; t < 12; ++t){
    if (t < 11){
      stageB(t + 1, buf ^ B6STR);
      #pragma unroll
      for (int mt = 0; mt < 4; ++mt)
        a_nxt[mt].u4 = *reinterpret_cast<const uint4*>(abase + mt * 6144 + (t + 1) * 32);
    }
    FragU bfr[3];
    #pragma unroll
    for (int nt = 0; nt < 3; ++nt){
      int rown = wc * 48 + nt * 16 + l15;
      int byte = buf + rown * 64 + ((lhi ^ ((rown >> 1) & 3)) << 4);
      bfr[nt].u4 = *reinterpret_cast<const uint4*>(smem + byte);
    }
    #pragma unroll
    for (int mt = 0; mt < 4; ++mt)
      #pragma unroll
      for (int nt = 0; nt < 3; ++nt)
        acc[mt][nt] = __builtin_amdgcn_mfma_f32_16x16x32_bf16(a_cur[mt].bf, bfr[nt].bf, acc[mt][nt], 0, 0, 0);
    __syncthreads();
    #pragma unroll
    for (int mt = 0; mt < 4; ++mt) a_cur[mt] = a_nxt[mt];
    buf ^= B6STR;
  }

  float bpv[3];
  #pragma unroll
  for (int nt = 0; nt < 3; ++nt) bpv[nt] = bp[ny * 192 + wc * 48 + nt * 16 + l15];
  #pragma unroll
  for (int mt = 0; mt < 4; ++mt)
    #pragma unroll
    for (int nt = 0; nt < 3; ++nt){
      const int ch = ny * 192 + wc * 48 + nt * 16 + l15;
      #pragma unroll
      for (int r = 0; r < 4; ++r){
        size_t grow = row0 + wr * 64 + mt * 16 + lhi * 4 + r;
        out[grow * 384 + ch] = acc[mt][nt][r] + bpv[nt];
      }
    }
}

extern "C" void kernel_launch(void* const* d_in, const int* in_sizes, int n_in,
                              void* d_out, int out_size, void* d_ws, size_t ws_size,
                              hipStream_t stream)
{
  const float* x  = (const float*)d_in[0];
  const float* wq = (const float*)d_in[1];
  const float* bq = (const float*)d_in[2];
  const float* wp = (const float*)d_in[3];
  const float* bp = (const float*)d_in[4];
  float* out = (float*)d_out;

  u16* wqb = (u16*)d_ws;                              // 442368 bf16
  u16* wpb = (u16*)((char*)d_ws + 442368 * 2);        // 147456 bf16
  u16* vws = (u16*)((char*)d_ws + 1179648);           // 2048*6*64*80 bf16 (125.8 MB)
  u16* xb  = (u16*)((char*)d_ws + 127008768);         // 147456*384 bf16 (113.2 MB)
  // ws_size >= 240254976 confirmed by rounds 5/7/9 (big2 path ran).

  prep_all<<<27648, 256, 0, stream>>>(x, xb, wq, wp, wqb, wpb);
  qkv_win<<<6144, 256, 0, stream>>>(xb, wqb, bq, out, vws);
  win_attn6<<<2048, 320, 0, stream>>>((const u16*)out, vws, out, xb);
  proj_gemm2<<<2304, 512, 0, stream>>>(xb, wpb, bp, out);
}

// Round 16
// 607.419 us; speedup vs baseline: 1.3345x; 1.1659x over previous
//
#include <hip/hip_runtime.h>

typedef __attribute__((ext_vector_type(8))) __bf16 bf16x8;
typedef __attribute__((ext_vector_type(4))) float f32x4;
typedef unsigned short u16;
typedef unsigned int u32;

__device__ __forceinline__ u16 f2bf(float x){
  u32 u = __float_as_uint(x);
  return (u16)((u + 0x7fffu + ((u >> 16) & 1u)) >> 16);
}
__device__ __forceinline__ u32 pkbf(float lo, float hi){
  u32 r; asm("v_cvt_pk_bf16_f32 %0, %1, %2" : "=v"(r) : "v"(lo), "v"(hi)); return r;
}

union FragU { uint4 u4; bf16x8 bf; };

__device__ __forceinline__ bf16x8 lds_frag(const unsigned char* smem, int off, int row, int strideB, int kElem){
  int byte = (row * strideB + kElem * 2) ^ ((row & 7) << 4);
  FragU f; f.u4 = *reinterpret_cast<const uint4*>(smem + off + byte);
  return f.bf;
}

typedef __attribute__((address_space(3))) unsigned char lds_u8;
typedef __attribute__((address_space(1))) const unsigned char g_u8;
__device__ __forceinline__ void glds16(const void* g, void* l){
  __builtin_amdgcn_global_load_lds((g_u8*)g, (lds_u8*)l, 16, 0, 0);
}

__global__ void prep_weights(const float* __restrict__ wq, const float* __restrict__ wp,
                             u16* __restrict__ wqb, u16* __restrict__ wpb){
  int i = blockIdx.x * 256 + threadIdx.x;
  wqb[i] = f2bf(wq[i]);              // grid sized exactly for 442368
  if (i < 147456) wpb[i] = f2bf(wp[i]);
}

// x f32 -> bf16, linear [147456][384]
__global__ void prep_x(const float* __restrict__ x, u16* __restrict__ xb){
  size_t i = ((size_t)blockIdx.x * 256 + threadIdx.x) * 8;
  float4 f0 = *reinterpret_cast<const float4*>(x + i);
  float4 f1 = *reinterpret_cast<const float4*>(x + i + 4);
  uint4 q;
  q.x = pkbf(f0.x, f0.y); q.y = pkbf(f0.z, f0.w);
  q.z = pkbf(f1.x, f1.y); q.w = pkbf(f1.z, f1.w);
  *reinterpret_cast<uint4*>(xb + i) = q;
}

// ======================================================================
// K2: WINDOW-MAJOR qkv GEMM (r11 structure). One (window, sec) per block,
// 256 thr. CHANGE vs r11 (isolated): q/k epilogue writes through a swizzled
// LDS transpose buffer QT [80tok][384ch] (aliases WA+WB post-loop) and then
// bulk-stores full 64B lines (uint4 x 4 lanes), replacing 48 scalar u16
// global stores/thread (partial-line HBM writes). v path unchanged.
// ======================================================================
#define WA_OFF 0        // A [80][64] bf16 swz : 10240
#define WB_OFF 10240    // B [384][64] bf16 swz : 49152 -> 59392
#define WVT    0        // v-transpose [384ch][80tok] (aliases A+B post-loop)
#define WQT    0        // q/k transpose [80tok][384ch] u16 = 61440 (aliases A+B)
#define WTC    61440    // 288 f32
#define WTS    62592    // -> 63744
__launch_bounds__(256, 2)
__global__ void qkv_win(const u16* __restrict__ xb, const u16* __restrict__ wqb,
                        const float* __restrict__ bq, float* __restrict__ out,
                        u16* __restrict__ vws)
{
  __shared__ __align__(16) unsigned char smem[63744];
  const int tid  = threadIdx.x;
  const int wc   = tid >> 6;            // wave 0..3 : 96-col quarter
  const int lane = tid & 63;
  const int l15  = lane & 15;
  const int lhi  = lane >> 4;

  const int bid = blockIdx.x;           // 0..6143 (= 8 * 768)
  const int l   = (bid & 7) * 768 + (bid >> 3);
  const int g   = l / 3;                // global window 0..2047
  const int sec = l - g * 3;            // 0=q,1=k,2=v
  const int bIdx = g >> 10;
  const int win  = g & 1023;
  const int wi   = win >> 5;
  const int wj   = win & 31;

  auto rowof = [&](int t)->size_t {
    int r = t / 12, c = t - r * 12;
    int hh = wi * 6 + r + 3;  if (hh >= 192) hh -= 192;
    int ww = wj * 12 + c + 6; if (ww >= 384) ww -= 384;
    return ((size_t)bIdx * 192 + hh) * 384 + ww;
  };

  float* tabc = reinterpret_cast<float*>(smem + WTC);
  float* tabs = reinterpret_cast<float*>(smem + WTS);
  for (int i = tid; i < 288; i += 256){
    int pos = i >> 4, m = i & 15;
    float pv = (pos < 6) ? (float)pos : (float)(pos - 6);
    float ang = pv * __expf(-(float)m * 0.5756462732485114f); // 10000^(-m/16)
    tabc[i] = cosf(ang);
    tabs[i] = sinf(ang);
  }

  // precompute A-chunk source rows (kk-invariant)
  size_t arow[3]; int asoff[3]; bool aval[3];
  #pragma unroll
  for (int it = 0; it < 3; ++it){
    int c = it * 256 + tid;
    aval[it] = (it < 2) || (tid < 128);
    int t = c >> 3, p = c & 7;
    int tc = (t < 72) ? t : 71;
    arow[it]  = rowof(tc);
    asoff[it] = ((p ^ (t & 7)) << 3);
  }

  f32x4 acc[5][6];
  #pragma unroll
  for (int mt = 0; mt < 5; ++mt)
    #pragma unroll
    for (int nt = 0; nt < 6; ++nt) acc[mt][nt] = 0.0f;

  for (int kk = 0; kk < 6; ++kk){
    #pragma unroll
    for (int it = 0; it < 3; ++it){
      if (aval[it])
        glds16(xb + arow[it] * 384 + kk * 64 + asoff[it],
               smem + WA_OFF + (it * 256 + tid) * 16);
    }
    #pragma unroll
    for (int it = 0; it < 12; ++it){
      int c = it * 256 + tid;
      int n = c >> 3, p = c & 7;
      glds16(wqb + (size_t)(sec * 384 + n) * 384 + kk * 64 + ((p ^ (n & 7)) << 3),
             smem + WB_OFF + c * 16);
    }
    __syncthreads();
    #pragma unroll
    for (int ks = 0; ks < 2; ++ks){
      const int kEl = ks * 32 + lhi * 8;
      bf16x8 af[5], bfr[6];
      #pragma unroll
      for (int mt = 0; mt < 5; ++mt)
        af[mt] = lds_frag(smem, WA_OFF, mt * 16 + l15, 128, kEl);
      #pragma unroll
      for (int nt = 0; nt < 6; ++nt)
        bfr[nt] = lds_frag(smem, WB_OFF, wc * 96 + nt * 16 + l15, 128, kEl);
      __builtin_amdgcn_s_setprio(1);
      #pragma unroll
      for (int mt = 0; mt < 5; ++mt)
        #pragma unroll
        for (int nt = 0; nt < 6; ++nt)
          acc[mt][nt] = __builtin_amdgcn_mfma_f32_16x16x32_bf16(af[mt], bfr[nt], acc[mt][nt], 0, 0, 0);
      __builtin_amdgcn_s_setprio(0);
    }
    __syncthreads();
  }

  if (sec < 2){
    // bias + RoPE -> swizzled LDS transpose QT [80tok][384ch]
    #pragma unroll
    for (int nt = 0; nt < 6; ++nt){
      const int ch  = wc * 96 + nt * 16 + l15;
      const int chh = ch & 63;
      const float bias = bq[sec * 384 + ch];
      const int p2  = chh >> 1;
      const int m   = p2 & 15;
      const bool isR = (p2 < 16);
      const bool ev  = ((chh & 1) == 0);
      #pragma unroll
      for (int mt = 0; mt < 5; ++mt){
        #pragma unroll
        for (int r = 0; r < 4; ++r){
          const int tok = mt * 16 + lhi * 4 + r;
          float v = acc[mt][nt][r] + bias;
          float o = __shfl_xor(v, 1);
          int tr = tok / 12;
          int pos = isR ? tr : (6 + tok - tr * 12);
          float cc = tabc[pos * 16 + m], ssn = tabs[pos * 16 + m];
          float nv = ev ? (v * cc - o * ssn) : (o * ssn + v * cc);
          if (sec == 0) nv *= 0.125f;
          int byte = (tok * 768 + ch * 2) ^ ((tok & 7) << 4);
          *reinterpret_cast<u16*>(smem + WQT + byte) = f2bf(nv);
        }
      }
    }
    __syncthreads();
    // bulk store: full 64B lines (4 lanes x uint4), rows tok<72 only
    u16* qk = (u16*)out + (sec ? 56623104u : 0u) + (size_t)g * 27648;  // [h][72][64]
    #pragma unroll
    for (int it = 0; it < 15; ++it){
      int c   = it * 256 + tid;          // 0..3839 ; 48 chunks per tok row
      int tok = c / 48;
      int p   = c - tok * 48;            // 0..47 ; h = p>>3, ch = (p&7)*8
      if (tok < 72){
        FragU f;
        f.u4 = *reinterpret_cast<const uint4*>(
                 smem + WQT + ((tok * 768 + p * 16) ^ ((tok & 7) << 4)));
        *reinterpret_cast<uint4*>(qk + (size_t)(p >> 3) * 4608 + tok * 64 + (p & 7) * 8) = f.u4;
      }
    }
  } else {
    #pragma unroll
    for (int nt = 0; nt < 6; ++nt){
      const int ch = wc * 96 + nt * 16 + l15;
      const float bv = bq[768 + ch];
      #pragma unroll
      for (int mt = 0; mt < 5; ++mt){
        const int tok0 = mt * 16 + lhi * 4;
        uint2 pk;
        pk.x = pkbf(acc[mt][nt][0] + bv, acc[mt][nt][1] + bv);
        pk.y = pkbf(acc[mt][nt][2] + bv, acc[mt][nt][3] + bv);
        *reinterpret_cast<uint2*>(smem + WVT + ch * 160 + tok0 * 2) = pk;
      }
    }
    __syncthreads();
    u16* vd = vws + (size_t)g * 30720;   // 6*64*80
    #pragma unroll
    for (int it = 0; it < 15; ++it){
      int c  = it * 256 + tid;           // 0..3839
      int ch = c / 10;
      int p  = c - ch * 10;
      uint4 val;
      if (p == 9){ val.x = 0; val.y = 0; val.z = 0; val.w = 0; }  // tok 72..79 = 0
      else val = *reinterpret_cast<const uint4*>(smem + WVT + c * 16);
      *reinterpret_cast<uint4*>(vd + (size_t)(ch >> 6) * 5120 + (ch & 63) * 80 + p * 8) = val;
    }
  }
}

// ============ K3: per-window attention (r11 win_attn6, unchanged) ============
#define QH4 0
#define KH4 10240
#define VT4 20480      // 64*160 + 256 guard -> 30976
#define SMEM4 30976
__launch_bounds__(320, 5)
__global__ void win_attn6(const u16* __restrict__ qkg,
                          const u16* __restrict__ vws,
                          float* __restrict__ out,
                          u16* __restrict__ axb)
{
  __shared__ __align__(16) unsigned char smem[SMEM4];
  const int tid  = threadIdx.x;
  const int wave = tid >> 6;
  const int lane = tid & 63;
  const int l15  = lane & 15;
  const int lhi  = lane >> 4;

  const int bid  = blockIdx.x;
  const int wgid = (bid & 7) * 256 + (bid >> 3);   // XCD swizzle (2048 = 8*256)
  const int bIdx = wgid >> 10;
  const int win  = wgid & 1023;
  const int wi   = win >> 5;
  const int wj   = win & 31;
  const bool maskWin = (wi == 31);
  const int g    = wgid;

  auto rowof = [&](int t)->size_t {
    int r = t / 12, c = t - r * 12;
    int hh = wi * 6 + r + 3;  if (hh >= 192) hh -= 192;
    int ww = wj * 12 + c + 6; if (ww >= 384) ww -= 384;
    return ((size_t)bIdx * 192 + hh) * 384 + ww;
  };
  const int qtok = wave * 16 + l15;     // 0..79
  const bool tv = (qtok < 72);
  const size_t qrow = rowof(tv ? qtok : 71);

  const u16* qsl0 = qkg + (size_t)g * 27648;
  const u16* ksl0 = qkg + 56623104u + (size_t)g * 27648;
  const u16* vsl0 = vws + (size_t)g * 30720;

  // zero the VT guard (row-overhang reads for kEl>=80 land here)
  if (tid < 64) *reinterpret_cast<u32*>(smem + VT4 + 10240 + tid * 4) = 0u;

  float sv[5][4];
  #pragma unroll
  for (int a2 = 0; a2 < 5; ++a2)
    #pragma unroll
    for (int b2 = 0; b2 < 4; ++b2) sv[a2][b2] = 0.0f;

  for (int h = 0; h < 6; ++h){
    const u16* qsl = qsl0 + h * 4608;
    const u16* ksl = ksl0 + h * 4608;
    const u16* vsl = vsl0 + h * 5120;
    #pragma unroll
    for (int it = 0; it < 2; ++it){
      int c = it * 320 + tid;           // 0..639
      int t = c >> 3, p = c & 7;
      int tc = (t < 72) ? t : 71;
      int s = (p ^ (t & 7)) << 3;
      glds16(qsl + tc * 64 + s, smem + QH4 + c * 16);
      glds16(ksl + tc * 64 + s, smem + KH4 + c * 16);
      glds16(vsl + c * 8,       smem + VT4 + c * 16);
    }
    __syncthreads();                    // stage visible

    f32x4 pf[5];
    #pragma unroll
    for (int nt = 0; nt < 5; ++nt) pf[nt] = 0.0f;
    __builtin_amdgcn_s_setprio(1);
    #pragma unroll
    for (int ks = 0; ks < 2; ++ks){
      const int kEl = ks * 32 + lhi * 8;
      bf16x8 qf = lds_frag(smem, QH4, qtok, 128, kEl);
      #pragma unroll
      for (int nt = 0; nt < 5; ++nt){
        bf16x8 kf = lds_frag(smem, KH4, nt * 16 + l15, 128, kEl);
        pf[nt] = __builtin_amdgcn_mfma_f32_16x16x32_bf16(kf, qf, pf[nt], 0, 0, 0);
      }
    }
    __builtin_amdgcn_s_setprio(0);

    float mx = -1e30f;
    #pragma unroll
    for (int nt = 0; nt < 5; ++nt)
      #pragma unroll
      for (int r = 0; r < 4; ++r){
        const int kk2 = nt * 16 + lhi * 4 + r;
        bool valid = (kk2 < 72) && (!maskWin || ((kk2 < 36) == (qtok < 36)));
        float val = valid ? pf[nt][r] : -1e30f;
        pf[nt][r] = val;
        mx = fmaxf(mx, val);
      }
    mx = fmaxf(mx, __shfl_xor(mx, 16));
    mx = fmaxf(mx, __shfl_xor(mx, 32));
    float sm = 0.0f;
    #pragma unroll
    for (int nt = 0; nt < 5; ++nt)
      #pragma unroll
      for (int r = 0; r < 4; ++r){
        float e = __expf(pf[nt][r] - mx);
        pf[nt][r] = e; sm += e;
      }
    sm += __shfl_xor(sm, 16);
    sm += __shfl_xor(sm, 32);
    const float inv = 1.0f / sm;
    u32 pp[5][2];                       // packed bf16 pairs: P[k..k+1][q=l15]
    #pragma unroll
    for (int nt = 0; nt < 5; ++nt){
      float p0 = pf[nt][0] * inv, p1 = pf[nt][1] * inv;
      float p2 = pf[nt][2] * inv, p3 = pf[nt][3] * inv;
      sv[nt][0] += p0; sv[nt][1] += p1; sv[nt][2] += p2; sv[nt][3] += p3;
      pp[nt][0] = pkbf(p0, p1);
      pp[nt][1] = pkbf(p2, p3);
    }

    f32x4 oacc[4];
    #pragma unroll
    for (int nt = 0; nt < 4; ++nt) oacc[nt] = 0.0f;
    #pragma unroll
    for (int ks = 0; ks < 3; ++ks){
      FragU pb;
      u32 w[4];
      #pragma unroll
      for (int w_ = 0; w_ < 4; ++w_){
        int srcLane = l15 + 16 * ((lane >> 4 & 1) * 2 + (w_ >> 1));
        u32 c0 = __shfl(pp[ks * 2][w_ & 1], srcLane);
        u32 c1 = (ks * 2 + 1 < 5) ? __shfl(pp[ks * 2 + 1][w_ & 1], srcLane) : 0u;
        w[w_] = (lhi & 2) ? c1 : c0;
      }
      pb.u4.x = w[0]; pb.u4.y = w[1]; pb.u4.z = w[2]; pb.u4.w = w[3];
      const int kEl = ks * 32 + lhi * 8;
      __builtin_amdgcn_s_setprio(1);
      #pragma unroll
      for (int nt = 0; nt < 4; ++nt){
        FragU vf;
        vf.u4 = *reinterpret_cast<const uint4*>(smem + VT4 + (nt * 16 + l15) * 160 + kEl * 2);
        oacc[nt] = __builtin_amdgcn_mfma_f32_16x16x32_bf16(vf.bf, pb.bf, oacc[nt], 0, 0, 0);
      }
      __builtin_amdgcn_s_setprio(0);
    }
    if (tv){
      u16* ao = axb + qrow * 384 + h * 64;
      #pragma unroll
      for (int nt = 0; nt < 4; ++nt){
        uint2 pk;
        pk.x = pkbf(oacc[nt][0], oacc[nt][1]);
        pk.y = pkbf(oacc[nt][2], oacc[nt][3]);
        *reinterpret_cast<uint2*>(ao + nt * 16 + lhi * 4) = pk;
      }
    }
    __syncthreads();                    // all LDS reads done before next stage
  } // heads

  if (tv){
    float* so = out + 56623104ull + (size_t)wgid * 5184 + (size_t)qtok * 72;
    const float c6 = 1.0f / 6.0f;
    #pragma unroll
    for (int nt = 0; nt < 4; ++nt){
      float4 v4; v4.x = sv[nt][0]*c6; v4.y = sv[nt][1]*c6; v4.z = sv[nt][2]*c6; v4.w = sv[nt][3]*c6;
      *reinterpret_cast<float4*>(so + nt * 16 + lhi * 4) = v4;
    }
    if (lhi < 2){
      float4 v4; v4.x = sv[4][0]*c6; v4.y = sv[4][1]*c6; v4.z = sv[4][2]*c6; v4.w = sv[4][3]*c6;
      *reinterpret_cast<float4*>(so + 64 + lhi * 4) = v4;
    }
  }
}

// ======================================================================
// K4: out-projection GEMM (r11 exact): tile M=128 x N=192, BK=32, 2-phase
// dbuf B, A frags direct from axb [row][384] u16. grid (1152, 2).
// ======================================================================
#define B6STR 12288
__launch_bounds__(512, 4)
__global__ void proj_gemm2(const u16* __restrict__ axb,
                           const u16* __restrict__ wpb, const float* __restrict__ bp,
                           float* __restrict__ out)
{
  __shared__ __align__(16) unsigned char smem[24576];
  const int tid  = threadIdx.x;
  const int wave = tid >> 6;
  const int lane = tid & 63;
  const int l15  = lane & 15;
  const int lhi  = lane >> 4;
  const int wr   = wave >> 2;
  const int wc   = wave & 3;
  const size_t row0 = (size_t)blockIdx.x * 128;
  const int ny   = blockIdx.y;

  const u16* bsec = wpb + (size_t)(ny * 192) * 384;
  auto stageB = [&](int t, int bufOff){
    {
      int c = tid, row = c >> 2, ccd = c & 3;
      int ccs = ccd ^ ((row >> 1) & 3);
      glds16(bsec + (size_t)row * 384 + t * 32 + ccs * 8, smem + bufOff + c * 16);
    }
    if (tid < 256){
      int c = 512 + tid, row = c >> 2, ccd = c & 3;
      int ccs = ccd ^ ((row >> 1) & 3);
      glds16(bsec + (size_t)row * 384 + t * 32 + ccs * 8, smem + bufOff + c * 16);
    }
  };

  const u16* abase = axb + (row0 + wr * 64 + l15) * 384 + lhi * 8;

  f32x4 acc[4][3];
  #pragma unroll
  for (int mt = 0; mt < 4; ++mt)
    #pragma unroll
    for (int nt = 0; nt < 3; ++nt) acc[mt][nt] = 0.0f;

  FragU a_cur[4], a_nxt[4];
  #pragma unroll
  for (int mt = 0; mt < 4; ++mt)
    a_cur[mt].u4 = *reinterpret_cast<const uint4*>(abase + mt * 6144);
  stageB(0, 0);
  __syncthreads();

  int buf = 0;
  for (int t = 0; t < 12; ++t){
    if (t < 11){
      stageB(t + 1, buf ^ B6STR);
      #pragma unroll
      for (int mt = 0; mt < 4; ++mt)
        a_nxt[mt].u4 = *reinterpret_cast<const uint4*>(abase + mt * 6144 + (t + 1) * 32);
    }
    FragU bfr[3];
    #pragma unroll
    for (int nt = 0; nt < 3; ++nt){
      int rown = wc * 48 + nt * 16 + l15;
      int byte = buf + rown * 64 + ((lhi ^ ((rown >> 1) & 3)) << 4);
      bfr[nt].u4 = *reinterpret_cast<const uint4*>(smem + byte);
    }
    #pragma unroll
    for (int mt = 0; mt < 4; ++mt)
      #pragma unroll
      for (int nt = 0; nt < 3; ++nt)
        acc[mt][nt] = __builtin_amdgcn_mfma_f32_16x16x32_bf16(a_cur[mt].bf, bfr[nt].bf, acc[mt][nt], 0, 0, 0);
    __syncthreads();
    #pragma unroll
    for (int mt = 0; mt < 4; ++mt) a_cur[mt] = a_nxt[mt];
    buf ^= B6STR;
  }

  float bpv[3];
  #pragma unroll
  for (int nt = 0; nt < 3; ++nt) bpv[nt] = bp[ny * 192 + wc * 48 + nt * 16 + l15];
  #pragma unroll
  for (int mt = 0; mt < 4; ++mt)
    #pragma unroll
    for (int nt = 0; nt < 3; ++nt){
      const int ch = ny * 192 + wc * 48 + nt * 16 + l15;
      #pragma unroll
      for (int r = 0; r < 4; ++r){
        size_t grow = row0 + wr * 64 + mt * 16 + lhi * 4 + r;
        out[grow * 384 + ch] = acc[mt][nt][r] + bpv[nt];
      }
    }
}

extern "C" void kernel_launch(void* const* d_in, const int* in_sizes, int n_in,
                              void* d_out, int out_size, void* d_ws, size_t ws_size,
                              hipStream_t stream)
{
  const float* x  = (const float*)d_in[0];
  const float* wq = (const float*)d_in[1];
  const float* bq = (const float*)d_in[2];
  const float* wp = (const float*)d_in[3];
  const float* bp = (const float*)d_in[4];
  float* out = (float*)d_out;

  u16* wqb = (u16*)d_ws;                              // 442368 bf16
  u16* wpb = (u16*)((char*)d_ws + 442368 * 2);        // 147456 bf16
  u16* vws = (u16*)((char*)d_ws + 1179648);           // 2048*6*64*80 bf16 (125.8 MB)
  u16* xb  = (u16*)((char*)d_ws + 127008768);         // 147456*384 bf16 (113.2 MB)
  // ws_size >= 240254976 confirmed by rounds 5/7/9 (big2 path ran).

  prep_weights<<<1728, 256, 0, stream>>>(wq, wp, wqb, wpb);
  prep_x<<<27648, 256, 0, stream>>>(x, xb);
  qkv_win<<<6144, 256, 0, stream>>>(xb, wqb, bq, out, vws);
  win_attn6<<<2048, 320, 0, stream>>>((const u16*)out, vws, out, xb);
  proj_gemm2<<<dim3(1152, 2), 512, 0, stream>>>(xb, wpb, bp, out);
}